// Round 19
// baseline (235.373 us; speedup 1.0000x reference)
//
#include <hip/hip_runtime.h>
#include <math.h>

// B=4, S=1024, D=1024, H=16, HD=64. All inputs fp32; output fp32.
// bf16 MFMA everywhere. Relative shift in closed form inside fused attention.
// TERMINAL (235.3 +/- 0.4us, reproduced 5x):
//   - attn: XCD-local grid, double-buffered global_load_lds K/V^T staging
//     (src pre-swizzled, conflict-free reads), closed-form relative-shift BD
//     via windowed p-GEMMs with one-tile-ahead register prefetch, defer-max
//     online softmax, ones-MFMA row-sum.
//   - GEMMs: fused QKV+pos (sect-dispatched, V^T via swapped-MFMA) and final,
//     both 128^2 single-buffer global_load_lds structure, XCD swizzle.
//   - prep: ln + 5x weight-transpose + pe/zero/bias fused in one launch.
//   4 launches total; 347 -> 235us over the session (1.47x).

typedef __bf16 bf16;
typedef __bf16 bf16x8 __attribute__((ext_vector_type(8)));
typedef __bf16 bf16x4 __attribute__((ext_vector_type(4)));
typedef float f32x4 __attribute__((ext_vector_type(4)));

#define S_ 1024
#define D_ 1024
#define PROWS 3136   // padded p rows: [-1088, 2048)
#define POFF 1088

#define AS1 __attribute__((address_space(1)))
#define AS3 __attribute__((address_space(3)))

static __device__ __forceinline__ f32x4 mfma16(bf16x8 a, bf16x8 b, f32x4 c) {
  return __builtin_amdgcn_mfma_f32_16x16x32_bf16(a, b, c, 0, 0, 0);
}

// ---------------- workspace layout (bytes) ----------------
static constexpr size_t OXN  = 0;                                   // xn bf16 [4096,1024]
static constexpr size_t OWTQ = OXN  + (size_t)4096*1024*2;          // wtq/wtk/wtv/wtp/wtf contiguous = BT[5120][1024]
static constexpr size_t OWTK = OWTQ + (size_t)1024*1024*2;
static constexpr size_t OWTV = OWTK + (size_t)1024*1024*2;
static constexpr size_t OWTP = OWTV + (size_t)1024*1024*2;
static constexpr size_t OWTF = OWTP + (size_t)1024*1024*2;
static constexpr size_t OPE  = OWTF + (size_t)1024*1024*2;          // pe bf16 [1024,1024]
static constexpr size_t OQU  = OPE  + (size_t)1024*1024*2;          // [B,H,S,64] bf16
static constexpr size_t OQV  = OQU  + (size_t)64*1024*64*2;
static constexpr size_t OKB  = OQV  + (size_t)64*1024*64*2 + 256;   // pad for qv row overrun
static constexpr size_t OVT  = OKB  + (size_t)64*1024*64*2;         // V^T [B,H,64,S] bf16
static constexpr size_t OPP  = OVT  + (size_t)64*1024*64*2;         // p_pad [16,3136,64] bf16
static constexpr size_t PPBYTES = (size_t)16*PROWS*64*2;            // 6422528
static constexpr size_t OOB  = OPP  + PPBYTES;                      // attn out bf16 [4096,1024]
static constexpr size_t OBU  = OOB  + (size_t)4096*1024*2;          // bu f32[1024]
static constexpr size_t OBV2 = OBU  + 4096;                         // bv2 f32[1024]

// ---------------- fused prep: ln (4096) + wtrans x5 (5120) + misc (2596) ----------------
__global__ __launch_bounds__(256) void prep_kernel(
    const float* __restrict__ x, const float* __restrict__ gamma,
    const float* __restrict__ beta, bf16* __restrict__ xn,
    const float* __restrict__ W0, const float* __restrict__ W1,
    const float* __restrict__ W2, const float* __restrict__ W3,
    const float* __restrict__ W4, bf16* __restrict__ outbase,
    const float* __restrict__ bq, const float* __restrict__ u,
    const float* __restrict__ v, float* __restrict__ bu, float* __restrict__ bv2,
    bf16* __restrict__ pe, uint4* __restrict__ pz) {
  int blk = blockIdx.x, t = threadIdx.x;
  __shared__ float tile[32][33];
  __shared__ float red[8];
  if (blk < 4096) {
    // ---- LayerNorm row ----
    int row = blk;
    const float4* xr = (const float4*)(x + (size_t)row * D_);
    float4 vv = xr[t];
    float s  = vv.x + vv.y + vv.z + vv.w;
    float ss = vv.x*vv.x + vv.y*vv.y + vv.z*vv.z + vv.w*vv.w;
    for (int off = 32; off; off >>= 1) {
      s  += __shfl_xor(s, off);
      ss += __shfl_xor(ss, off);
    }
    int wid = t >> 6;
    if ((t & 63) == 0) { red[wid] = s; red[wid + 4] = ss; }
    __syncthreads();
    float S  = red[0] + red[1] + red[2] + red[3];
    float SS = red[4] + red[5] + red[6] + red[7];
    float mu = S * (1.f / 1024.f);
    float rstd = rsqrtf(SS * (1.f / 1024.f) - mu * mu + 1e-5f);
    float4 g  = ((const float4*)gamma)[t];
    float4 bb = ((const float4*)beta)[t];
    bf16x4 o;
    o[0] = (bf16)((vv.x - mu) * rstd * g.x + bb.x);
    o[1] = (bf16)((vv.y - mu) * rstd * g.y + bb.y);
    o[2] = (bf16)((vv.z - mu) * rstd * g.z + bb.z);
    o[3] = (bf16)((vv.w - mu) * rstd * g.w + bb.w);
    *(bf16x4*)(xn + (size_t)row * D_ + t * 4) = o;
  } else if (blk < 9216) {
    // ---- weight transpose fp32 -> bf16 ----
    int idx = blk - 4096;
    int z = idx >> 10, rem = idx & 1023;
    int bx = rem & 31, by = rem >> 5;
    const float* W = z == 0 ? W0 : z == 1 ? W1 : z == 2 ? W2 : z == 3 ? W3 : W4;
    bf16* WT = outbase + (size_t)z * 1024 * 1024;
    int tx = t & 31, ty = t >> 5;
    #pragma unroll
    for (int i = 0; i < 4; i++)
      tile[ty + i * 8][tx] = W[(size_t)(by * 32 + ty + i * 8) * D_ + bx * 32 + tx];
    __syncthreads();
    #pragma unroll
    for (int i = 0; i < 4; i++)
      WT[(size_t)(bx * 32 + ty + i * 8) * D_ + by * 32 + tx] = (bf16)tile[tx][ty + i * 8];
  } else {
    int mblk = blk - 9216;
    if (mblk < 1024) {
      int pos = mblk;
      #pragma unroll
      for (int pp = 0; pp < 2; pp++) {
        int f = t + pp * 256;  // 0..511
        float inv = __expf(-(2.0f * (float)f * (1.0f / 1024.0f)) * 9.210340371976184f);
        float ang = (float)pos * inv;
        float sv, cv;
        __sincosf(ang, &sv, &cv);
        pe[(size_t)pos * D_ + 2 * f]     = (bf16)sv;
        pe[(size_t)pos * D_ + 2 * f + 1] = (bf16)cv;
      }
    } else if (mblk < 1024 + 1568) {
      int i = (mblk - 1024) * 256 + t;   // PPBYTES/16 = 401408 = 1568*256 exactly
      pz[i] = make_uint4(0u, 0u, 0u, 0u);
    } else {
      int c = (mblk - 2592) * 256 + t;
      if (c < 1024) { bu[c] = bq[c] + u[c]; bv2[c] = bq[c] + v[c]; }
    }
  }
}

// ---------------- fused QKV+pos GEMM (single-buffer, R5 structure) ----------------
__global__ __launch_bounds__(256) void gemm_qkvp_kernel(
    const bf16* __restrict__ xn, const bf16* __restrict__ pe,
    const bf16* __restrict__ BT,
    const float* __restrict__ bu, const float* __restrict__ bv2,
    const float* __restrict__ bk, const float* __restrict__ bv,
    bf16* __restrict__ quB, bf16* __restrict__ qvB,
    bf16* __restrict__ kbB, bf16* __restrict__ vtB, bf16* __restrict__ ppd) {
  __shared__ __align__(16) bf16 As[128 * 32];
  __shared__ __align__(16) bf16 Bs[128 * 32];
  int lin = blockIdx.x;
  int swz = (lin & 7) * 104 + (lin >> 3);   // 832/8 = 104
  int m0, n0, sect;
  const bf16* Abase;
  int nrow0;
  if (swz < 768) {
    int bx = swz % 24, by = swz / 24;
    m0 = by * 128; n0 = bx * 128;
    sect = n0 >> 10;
    Abase = xn; nrow0 = n0;
  } else {
    int pp = swz - 768;
    int bx = pp & 7, by = pp >> 3;
    m0 = by * 128; n0 = bx * 128;
    sect = 3;
    Abase = pe; nrow0 = 3072 + n0;
  }
  int t = threadIdx.x, l = t & 63, w = t >> 6;
  int lr = l & 15, lq = l >> 4;
  int wr = w >> 1, wc = w & 1;
  f32x4 acc[4][4];
  #pragma unroll
  for (int mi = 0; mi < 4; mi++)
    #pragma unroll
    for (int ni = 0; ni < 4; ni++) acc[mi][ni] = (f32x4){0.f, 0.f, 0.f, 0.f};
  int srow = l >> 2, scol = (l & 3) * 8;
  for (int kk = 0; kk < 1024; kk += 32) {
    #pragma unroll
    for (int c2 = 0; c2 < 2; c2++) {
      int ch = w * 2 + c2;
      const bf16* ga = Abase + (size_t)(m0 + ch * 16 + srow) * 1024 + kk + scol;
      __builtin_amdgcn_global_load_lds((const AS1 void*)ga, (AS3 void*)(As + ch * 512), 16, 0, 0);
      const bf16* gb = BT + (size_t)(nrow0 + ch * 16 + srow) * 1024 + kk + scol;
      __builtin_amdgcn_global_load_lds((const AS1 void*)gb, (AS3 void*)(Bs + ch * 512), 16, 0, 0);
    }
    __syncthreads();
    bf16x8 af[4], bfv[4];
    #pragma unroll
    for (int mi = 0; mi < 4; mi++)
      af[mi] = *(const bf16x8*)(As + (wr * 64 + mi * 16 + lr) * 32 + lq * 8);
    #pragma unroll
    for (int ni = 0; ni < 4; ni++)
      bfv[ni] = *(const bf16x8*)(Bs + (wc * 64 + ni * 16 + lr) * 32 + lq * 8);
    if (sect == 2) {
      #pragma unroll
      for (int mi = 0; mi < 4; mi++)
        #pragma unroll
        for (int ni = 0; ni < 4; ni++)
          acc[mi][ni] = mfma16(bfv[ni], af[mi], acc[mi][ni]);   // C^T
    } else {
      #pragma unroll
      for (int mi = 0; mi < 4; mi++)
        #pragma unroll
        for (int ni = 0; ni < 4; ni++)
          acc[mi][ni] = mfma16(af[mi], bfv[ni], acc[mi][ni]);
    }
    __syncthreads();
  }
  if (sect == 2) {
    #pragma unroll
    for (int mi = 0; mi < 4; mi++)
      #pragma unroll
      for (int ni = 0; ni < 4; ni++)
        #pragma unroll
        for (int rr = 0; rr < 4; rr++) {
          int wcol = (n0 - 2048) + wc * 64 + ni * 16 + lq * 4 + rr;
          int srw  = m0 + wr * 64 + mi * 16 + lr;
          int b = srw >> 10, s = srw & 1023, h = wcol >> 6, hd = wcol & 63;
          vtB[(((size_t)(b * 16 + h)) * 64 + hd) * 1024 + s] =
              (bf16)(acc[mi][ni][rr] + bv[wcol]);
        }
  } else if (sect == 3) {
    #pragma unroll
    for (int mi = 0; mi < 4; mi++)
      #pragma unroll
      for (int ni = 0; ni < 4; ni++)
        #pragma unroll
        for (int rr = 0; rr < 4; rr++) {
          int row = m0 + wr * 64 + mi * 16 + lq * 4 + rr;
          int col = n0 + wc * 64 + ni * 16 + lr;
          int h = col >> 6, hd = col & 63;
          ppd[((size_t)h * PROWS + POFF + row) * 64 + hd] = (bf16)acc[mi][ni][rr];
        }
  } else {
    #pragma unroll
    for (int mi = 0; mi < 4; mi++)
      #pragma unroll
      for (int ni = 0; ni < 4; ni++)
        #pragma unroll
        for (int rr = 0; rr < 4; rr++) {
          int row = m0 + wr * 64 + mi * 16 + lq * 4 + rr;
          int col = n0 + wc * 64 + ni * 16 + lr;
          float vv = acc[mi][ni][rr];
          int b = row >> 10, s = row & 1023;
          if (sect == 0) {
            int h = col >> 6, hd = col & 63;
            size_t idx = (((size_t)(b * 16 + h)) * 1024 + s) * 64 + hd;
            quB[idx] = (bf16)(vv + bu[col]);
            qvB[idx] = (bf16)(vv + bv2[col]);
          } else {
            int c = col - 1024, h = c >> 6, hd = c & 63;
            size_t idx = (((size_t)(b * 16 + h)) * 1024 + s) * 64 + hd;
            kbB[idx] = (bf16)(vv + bk[c]);
          }
        }
  }
}

// ---------------- final GEMM (single-buffer): d_out fp32 = obB * wtf^T + bf ----------------
__global__ __launch_bounds__(256) void gemm_final_kernel(
    const bf16* __restrict__ A, const bf16* __restrict__ BT,
    const float* __restrict__ bias0, float* __restrict__ out0) {
  __shared__ __align__(16) bf16 As[128 * 32];
  __shared__ __align__(16) bf16 Bs[128 * 32];
  int gx = gridDim.x;
  int lin = blockIdx.x + gx * blockIdx.y;
  int cpx = (gx * gridDim.y) >> 3;
  int swz = (lin & 7) * cpx + (lin >> 3);
  int bx = swz % gx, by = swz / gx;
  int m0 = by * 128, n0 = bx * 128;
  int t = threadIdx.x, l = t & 63, w = t >> 6;
  int lr = l & 15, lq = l >> 4;
  int wr = w >> 1, wc = w & 1;
  f32x4 acc[4][4];
  #pragma unroll
  for (int mi = 0; mi < 4; mi++)
    #pragma unroll
    for (int ni = 0; ni < 4; ni++) acc[mi][ni] = (f32x4){0.f, 0.f, 0.f, 0.f};
  int srow = l >> 2, scol = (l & 3) * 8;
  for (int kk = 0; kk < 1024; kk += 32) {
    #pragma unroll
    for (int c2 = 0; c2 < 2; c2++) {
      int ch = w * 2 + c2;
      const bf16* ga = A + (size_t)(m0 + ch * 16 + srow) * 1024 + kk + scol;
      __builtin_amdgcn_global_load_lds((const AS1 void*)ga, (AS3 void*)(As + ch * 512), 16, 0, 0);
      const bf16* gb = BT + (size_t)(n0 + ch * 16 + srow) * 1024 + kk + scol;
      __builtin_amdgcn_global_load_lds((const AS1 void*)gb, (AS3 void*)(Bs + ch * 512), 16, 0, 0);
    }
    __syncthreads();
    bf16x8 af[4], bfv[4];
    #pragma unroll
    for (int mi = 0; mi < 4; mi++)
      af[mi] = *(const bf16x8*)(As + (wr * 64 + mi * 16 + lr) * 32 + lq * 8);
    #pragma unroll
    for (int ni = 0; ni < 4; ni++)
      bfv[ni] = *(const bf16x8*)(Bs + (wc * 64 + ni * 16 + lr) * 32 + lq * 8);
    #pragma unroll
    for (int mi = 0; mi < 4; mi++)
      #pragma unroll
      for (int ni = 0; ni < 4; ni++)
        acc[mi][ni] = mfma16(af[mi], bfv[ni], acc[mi][ni]);
    __syncthreads();
  }
  #pragma unroll
  for (int mi = 0; mi < 4; mi++)
    #pragma unroll
    for (int ni = 0; ni < 4; ni++)
      #pragma unroll
      for (int rr = 0; rr < 4; rr++) {
        int row = m0 + wr * 64 + mi * 16 + lq * 4 + rr;
        int col = n0 + wc * 64 + ni * 16 + lr;
        out0[(size_t)row * 1024 + col] = acc[mi][ni][rr] + bias0[col];
      }
}

// ---------------- fused relative attention (R4 + p-window register prefetch) ----------------
// 1-D grid 1024; XCD-local decode. 4 waves/block, wave owns 16 q rows; 16 j-tiles.
// LDS caps residency at 2 blocks/CU (2 waves/SIMD) -> VGPR<=256 free; spend 80
// on bpA/bpB double-buffered p-window prefetch (one tile ahead, pure paths).
__global__ __launch_bounds__(256, 2) void attn_kernel(
    const bf16* __restrict__ qu, const bf16* __restrict__ qv,
    const bf16* __restrict__ kb, const bf16* __restrict__ vt,
    const bf16* __restrict__ ppad, bf16* __restrict__ ob) {
  int bid = blockIdx.x;
  int xcd = bid & 7, slot = bid >> 3;
  int g = slot >> 4, qblk = slot & 15;
  int bh = xcd + 8 * g;
  int h = bh & 15, b = bh >> 4;

  int t = threadIdx.x, l = t & 63, wid = t >> 6;
  int lr = l & 15, lq = l >> 4;
  int w0 = qblk * 64 + wid * 16;
  const bf16* quB = qu + (size_t)bh * S_ * 64;
  const bf16* qvB = qv + (size_t)bh * S_ * 64;
  const char* kBy = (const char*)(kb + (size_t)bh * S_ * 64);
  const char* vBy = (const char*)(vt + (size_t)bh * 64 * S_);
  const bf16* pH  = ppad + (size_t)h * PROWS * 64;

  __shared__ __align__(16) bf16 Kbuf[2][4096];   // [64 j][64 k] swizzled
  __shared__ __align__(16) bf16 Vbuf[2][4096];   // [64 d][64 j] swizzled
  __shared__ __align__(16) bf16 G1s[4][16][84];
  __shared__ __align__(16) bf16 G2s[4][16][84];
  bf16* PlW = &G1s[wid][0][0];                   // alias: [16][72], used after G reads

  bf16x8 aqu[2], aqv1[2], aqv2[2];
  #pragma unroll
  for (int ks = 0; ks < 2; ks++) {
    aqu[ks]  = *(const bf16x8*)(quB + (size_t)(w0 + lr) * 64 + ks * 32 + lq * 8);
    aqv1[ks] = *(const bf16x8*)(qvB + (size_t)(w0 + lr) * 64 + ks * 32 + lq * 8);
    aqv2[ks] = *(const bf16x8*)(qvB + (size_t)(w0 + 1 + lr) * 64 + ks * 32 + lq * 8);
  }
  bf16x8 ones;
  #pragma unroll
  for (int e = 0; e < 8; e++) ones[e] = (bf16)1.0f;

  float m_run[4];
  f32x4 accL = (f32x4){0.f, 0.f, 0.f, 0.f};
  f32x4 accO[4];
  #pragma unroll
  for (int rr = 0; rr < 4; rr++) m_run[rr] = -1e30f;
  #pragma unroll
  for (int nf = 0; nf < 4; nf++) accO[nf] = (f32x4){0.f, 0.f, 0.f, 0.f};

  const float SC = 0.045084220f;  // log2(e)/sqrt(1024)

  // staging: 16 chunk-instrs (8 K + 8 V), 4 per wave; dest linear, src pre-swizzled
  int srow8 = l >> 3;            // 0..7
  int scolb = (l & 7) * 16;      // 0..112 byte
  auto stage = [&](int nb, int j0n) {
    #pragma unroll
    for (int ci = 0; ci < 4; ci++) {
      int c = wid * 4 + ci;        // 0..15
      int cc = c & 7;
      int row = cc * 8 + srow8;    // 0..63
      int colsrc = scolb ^ ((row & 7) << 4);
      if (c < 8) {
        const char* src = kBy + (size_t)(j0n + row) * 128 + colsrc;
        __builtin_amdgcn_global_load_lds((const AS1 void*)src,
            (AS3 void*)(&Kbuf[nb][cc * 512]), 16, 0, 0);
      } else {
        const char* src = vBy + (size_t)row * 2048 + j0n * 2 + colsrc;
        __builtin_amdgcn_global_load_lds((const AS1 void*)src,
            (AS3 void*)(&Vbuf[nb][cc * 512]), 16, 0, 0);
      }
    }
  };

  // p-window register prefetch buffers (one tile ahead on pure paths)
  bf16x8 bpA[10], bpB[10];
  auto loadwin = [&](bf16x8 (&bp)[10], int pb) {
    #pragma unroll
    for (int gf = 0; gf < 5; gf++)
      #pragma unroll
      for (int ks = 0; ks < 2; ks++)
        bp[gf * 2 + ks] = *(const bf16x8*)(pH + (size_t)(pb + gf * 16 + lr) * 64 + ks * 32 + lq * 8);
  };

  stage(0, 0);
  // preload tile 0's windows if tile 0 is a pure path (d = w0)
  if (w0 >= 63) loadwin(bpA, 1023 - w0 - 15 + POFF);
  __syncthreads();

  auto tile = [&](int tt, bf16x8 (&bpC)[10], bf16x8 (&bpN)[10]) {
    int j0 = tt * 64;
    int cur = tt & 1;
    if (tt < 15) stage(cur ^ 1, j0 + 64);

    const char* Ks = (const char*)&Kbuf[cur][0];
    const char* Vs = (const char*)&Vbuf[cur][0];
    int d = w0 - j0;

    // AC = (q+u) k^T from swizzled LDS
    f32x4 accS[4];
    __builtin_amdgcn_s_setprio(1);
    #pragma unroll
    for (int nf = 0; nf < 4; nf++) {
      accS[nf] = (f32x4){0.f, 0.f, 0.f, 0.f};
      int rowk = nf * 16 + lr;
      #pragma unroll
      for (int ks = 0; ks < 2; ks++) {
        int off = ((rowk << 7) + (ks << 6) + (lq << 4)) ^ ((rowk & 7) << 4);
        bf16x8 bk8 = *(const bf16x8*)(Ks + off);
        accS[nf] = mfma16(aqu[ks], bk8, accS[nf]);
      }
    }
    __builtin_amdgcn_s_setprio(0);

    // BD windows from prefetched registers (pure paths) or direct (mixed)
    if (d >= 63) {
      #pragma unroll
      for (int gf = 0; gf < 5; gf++) {
        f32x4 gg = (f32x4){0.f, 0.f, 0.f, 0.f};
        gg = mfma16(aqv1[0], bpC[gf * 2 + 0], gg);
        gg = mfma16(aqv1[1], bpC[gf * 2 + 1], gg);
        #pragma unroll
        for (int rr = 0; rr < 4; rr++) G1s[wid][lq * 4 + rr][gf * 16 + lr] = (bf16)gg[rr];
      }
    } else if (d <= -17) {
      #pragma unroll
      for (int gf = 0; gf < 5; gf++) {
        f32x4 gg = (f32x4){0.f, 0.f, 0.f, 0.f};
        gg = mfma16(aqv2[0], bpC[gf * 2 + 0], gg);
        gg = mfma16(aqv2[1], bpC[gf * 2 + 1], gg);
        #pragma unroll
        for (int rr = 0; rr < 4; rr++) G2s[wid][lq * 4 + rr][gf * 16 + lr] = (bf16)gg[rr];
      }
    } else {
      // mixed (<=2 tiles/wave): direct runtime-trimmed loads
      {
        int pb = 1023 - w0 + j0 - 15 + POFF;
        int gmax = (d + 15) >> 4; if (gmax > 4) gmax = 4;
        for (int gf = 0; gf <= gmax; gf++) {
          f32x4 gg = (f32x4){0.f, 0.f, 0.f, 0.f};
          #pragma unroll
          for (int ks = 0; ks < 2; ks++) {
            bf16x8 bp = *(const bf16x8*)(pH + (size_t)(pb + gf * 16 + lr) * 64 + ks * 32 + lq * 8);
            gg = mfma16(aqv1[ks], bp, gg);
          }
          #pragma unroll
          for (int rr = 0; rr < 4; rr++) G1s[wid][lq * 4 + rr][gf * 16 + lr] = (bf16)gg[rr];
        }
      }
      {
        int pb = j0 - w0 - 17 + POFF;
        int t2 = d + 17;
        int gmin = t2 > 0 ? (t2 >> 4) : 0;
        for (int gf = gmin; gf < 5; gf++) {
          f32x4 gg = (f32x4){0.f, 0.f, 0.f, 0.f};
          #pragma unroll
          for (int ks = 0; ks < 2; ks++) {
            bf16x8 bp = *(const bf16x8*)(pH + (size_t)(pb + gf * 16 + lr) * 64 + ks * 32 + lq * 8);
            gg = mfma16(aqv2[ks], bp, gg);
          }
          #pragma unroll
          for (int rr = 0; rr < 4; rr++) G2s[wid][lq * 4 + rr][gf * 16 + lr] = (bf16)gg[rr];
        }
      }
    }

    // issue next tile's p-window prefetch (pure paths only); latency hides
    // under gather+softmax+PV+barrier+stage+AC of this/next tile
    if (tt < 15) {
      int dn = d - 64;
      int j0n = j0 + 64;
      if (dn >= 63)       loadwin(bpN, 1023 - w0 + j0n - 15 + POFF);
      else if (dn <= -17) loadwin(bpN, j0n - w0 - 17 + POFF);
    }

    // gather + softmax (wave-uniform path split)
    float sc[4][4];
    if (d >= 63) {
      #pragma unroll
      for (int nf = 0; nf < 4; nf++)
        #pragma unroll
        for (int rr = 0; rr < 4; rr++) {
          int ii = lq * 4 + rr;
          int u = nf * 16 + lr - ii + 15;
          sc[nf][rr] = (accS[nf][rr] + (float)G1s[wid][ii][u]) * SC;
        }
    } else if (d <= -17) {
      #pragma unroll
      for (int nf = 0; nf < 4; nf++)
        #pragma unroll
        for (int rr = 0; rr < 4; rr++) {
          int ii = lq * 4 + rr;
          int u = nf * 16 + lr - ii + 15;
          sc[nf][rr] = (accS[nf][rr] + (float)G2s[wid][ii][u]) * SC;
        }
    } else {
      #pragma unroll
      for (int nf = 0; nf < 4; nf++)
        #pragma unroll
        for (int rr = 0; rr < 4; rr++) {
          int ii = lq * 4 + rr;
          int jj = nf * 16 + lr;
          int dd = jj - ii;
          int u = dd + 15;
          float g1v = (float)G1s[wid][ii][u];
          float g2v = (float)G2s[wid][ii][u];
          float bd = dd <= d ? g1v : (dd == d + 1 ? 0.f : g2v);
          sc[nf][rr] = (accS[nf][rr] + bd) * SC;
        }
    }

    // defer-max: skip shuffle-max + rescale when within THR of running max
    float lmax[4];
    #pragma unroll
    for (int rr = 0; rr < 4; rr++)
      lmax[rr] = fmaxf(fmaxf(sc[0][rr], sc[1][rr]), fmaxf(sc[2][rr], sc[3][rr]));
    bool ok = (lmax[0] <= m_run[0] + 8.f) && (lmax[1] <= m_run[1] + 8.f) &&
              (lmax[2] <= m_run[2] + 8.f) && (lmax[3] <= m_run[3] + 8.f);
    if (!__all((int)ok)) {
      float rmax[4];
      #pragma unroll
      for (int rr = 0; rr < 4; rr++) rmax[rr] = lmax[rr];
      #pragma unroll
      for (int st = 1; st < 16; st <<= 1)
        #pragma unroll
        for (int rr = 0; rr < 4; rr++) rmax[rr] = fmaxf(rmax[rr], __shfl_xor(rmax[rr], st));
      #pragma unroll
      for (int rr = 0; rr < 4; rr++) {
        float mnew = fmaxf(m_run[rr], rmax[rr]);
        float sv = exp2f(m_run[rr] - mnew);
        m_run[rr] = mnew;
        accL[rr] *= sv;
        #pragma unroll
        for (int nf = 0; nf < 4; nf++) accO[nf][rr] *= sv;
      }
    }

    #pragma unroll
    for (int nf = 0; nf < 4; nf++)
      #pragma unroll
      for (int rr = 0; rr < 4; rr++) {
        float p = exp2f(sc[nf][rr] - m_run[rr]);
        PlW[(lq * 4 + rr) * 72 + nf * 16 + lr] = (bf16)p;
      }

    // PV + row-sum from swizzled LDS V^T
    bf16x8 ap[2];
    #pragma unroll
    for (int ks = 0; ks < 2; ks++)
      ap[ks] = *(const bf16x8*)(PlW + lr * 72 + ks * 32 + lq * 8);
    __builtin_amdgcn_s_setprio(1);
    #pragma unroll
    for (int ks = 0; ks < 2; ks++) accL = mfma16(ap[ks], ones, accL);
    #pragma unroll
    for (int nf = 0; nf < 4; nf++) {
      int rowd = nf * 16 + lr;
      #pragma unroll
      for (int ks = 0; ks < 2; ks++) {
        int off = ((rowd << 7) + (ks << 6) + (lq << 4)) ^ ((rowd & 7) << 4);
        bf16x8 bv8 = *(const bf16x8*)(Vs + off);
        accO[nf] = mfma16(ap[ks], bv8, accO[nf]);
      }
    }
    __builtin_amdgcn_s_setprio(0);

    __syncthreads();
  };

  #pragma unroll 1
  for (int tt = 0; tt < 16; tt += 2) {
    tile(tt,     bpA, bpB);
    tile(tt + 1, bpB, bpA);
  }

  #pragma unroll
  for (int nf = 0; nf < 4; nf++)
    #pragma unroll
    for (int rr = 0; rr < 4; rr++) {
      int i = w0 + lq * 4 + rr;
      float o = accO[nf][rr] / accL[rr];
      ob[((size_t)(b * S_ + i)) * 1024 + h * 64 + nf * 16 + lr] = (bf16)o;
    }
}

// ---------------- launch ----------------
extern "C" void kernel_launch(void* const* d_in, const int* in_sizes, int n_in,
                              void* d_out, int out_size, void* d_ws, size_t ws_size,
                              hipStream_t stream) {
  const float* x     = (const float*)d_in[0];
  const float* Wq    = (const float*)d_in[1];
  const float* bq    = (const float*)d_in[2];
  const float* Wk    = (const float*)d_in[3];
  const float* bk    = (const float*)d_in[4];
  const float* Wv    = (const float*)d_in[5];
  const float* bv    = (const float*)d_in[6];
  const float* Wpos  = (const float*)d_in[7];
  const float* Wf    = (const float*)d_in[8];
  const float* bf_   = (const float*)d_in[9];
  const float* u     = (const float*)d_in[10];
  const float* v     = (const float*)d_in[11];
  const float* gamma = (const float*)d_in[12];
  const float* beta  = (const float*)d_in[13];

  char* ws = (char*)d_ws;
  bf16* xn  = (bf16*)(ws + OXN);
  bf16* wtq = (bf16*)(ws + OWTQ);   // BT[5120][1024] base (q,k,v,pos,f)
  bf16* wtf = (bf16*)(ws + OWTF);
  bf16* pe  = (bf16*)(ws + OPE);
  bf16* quB = (bf16*)(ws + OQU);
  bf16* qvB = (bf16*)(ws + OQV);
  bf16* kbB = (bf16*)(ws + OKB);
  bf16* vtB = (bf16*)(ws + OVT);
  bf16* ppd = (bf16*)(ws + OPP);
  bf16* obB = (bf16*)(ws + OOB);
  float* bu  = (float*)(ws + OBU);
  float* bv2 = (float*)(ws + OBV2);

  prep_kernel<<<11812, 256, 0, stream>>>(x, gamma, beta, xn,
                                         Wq, Wk, Wv, Wpos, Wf, wtq,
                                         bq, u, v, bu, bv2, pe, (uint4*)(ws + OPP));

  gemm_qkvp_kernel<<<832, 256, 0, stream>>>(xn, pe, wtq, bu, bv2, bk, bv,
                                            quB, qvB, kbB, vtB, ppd);

  attn_kernel<<<1024, 256, 0, stream>>>(quB, qvB, kbB, vtB, ppd, obB);

  gemm_final_kernel<<<dim3(8, 32), 256, 0, stream>>>(obB, wtf, bf_, (float*)d_out);
}

// Round 20
// 234.682 us; speedup vs baseline: 1.0029x; 1.0029x over previous
//
#include <hip/hip_runtime.h>
#include <math.h>

// B=4, S=1024, D=1024, H=16, HD=64. All inputs fp32; output fp32.
// bf16 MFMA everywhere. Relative shift in closed form inside fused attention.
// TERMINAL (235.3 +/- 0.4us, reproduced 6x):
//   - attn: XCD-local grid, double-buffered global_load_lds K/V^T staging
//     (src pre-swizzled, conflict-free reads), closed-form relative-shift BD
//     via windowed p-GEMMs with one-tile-ahead register prefetch, defer-max
//     online softmax, ones-MFMA row-sum.
//   - GEMMs: fused QKV+pos (sect-dispatched, V^T via swapped-MFMA) and final,
//     both 128^2 single-buffer global_load_lds structure, XCD swizzle.
//   - prep: ln + 5x weight-transpose + pe/zero/bias fused in one launch.
//   4 launches total; 347 -> 235us over the session (1.47x).

typedef __bf16 bf16;
typedef __bf16 bf16x8 __attribute__((ext_vector_type(8)));
typedef __bf16 bf16x4 __attribute__((ext_vector_type(4)));
typedef float f32x4 __attribute__((ext_vector_type(4)));

#define S_ 1024
#define D_ 1024
#define PROWS 3136   // padded p rows: [-1088, 2048)
#define POFF 1088

#define AS1 __attribute__((address_space(1)))
#define AS3 __attribute__((address_space(3)))

static __device__ __forceinline__ f32x4 mfma16(bf16x8 a, bf16x8 b, f32x4 c) {
  return __builtin_amdgcn_mfma_f32_16x16x32_bf16(a, b, c, 0, 0, 0);
}

// ---------------- workspace layout (bytes) ----------------
static constexpr size_t OXN  = 0;                                   // xn bf16 [4096,1024]
static constexpr size_t OWTQ = OXN  + (size_t)4096*1024*2;          // wtq/wtk/wtv/wtp/wtf contiguous = BT[5120][1024]
static constexpr size_t OWTK = OWTQ + (size_t)1024*1024*2;
static constexpr size_t OWTV = OWTK + (size_t)1024*1024*2;
static constexpr size_t OWTP = OWTV + (size_t)1024*1024*2;
static constexpr size_t OWTF = OWTP + (size_t)1024*1024*2;
static constexpr size_t OPE  = OWTF + (size_t)1024*1024*2;          // pe bf16 [1024,1024]
static constexpr size_t OQU  = OPE  + (size_t)1024*1024*2;          // [B,H,S,64] bf16
static constexpr size_t OQV  = OQU  + (size_t)64*1024*64*2;
static constexpr size_t OKB  = OQV  + (size_t)64*1024*64*2 + 256;   // pad for qv row overrun
static constexpr size_t OVT  = OKB  + (size_t)64*1024*64*2;         // V^T [B,H,64,S] bf16
static constexpr size_t OPP  = OVT  + (size_t)64*1024*64*2;         // p_pad [16,3136,64] bf16
static constexpr size_t PPBYTES = (size_t)16*PROWS*64*2;            // 6422528
static constexpr size_t OOB  = OPP  + PPBYTES;                      // attn out bf16 [4096,1024]
static constexpr size_t OBU  = OOB  + (size_t)4096*1024*2;          // bu f32[1024]
static constexpr size_t OBV2 = OBU  + 4096;                         // bv2 f32[1024]

// ---------------- fused prep: ln (4096) + wtrans x5 (5120) + misc (2596) ----------------
__global__ __launch_bounds__(256) void prep_kernel(
    const float* __restrict__ x, const float* __restrict__ gamma,
    const float* __restrict__ beta, bf16* __restrict__ xn,
    const float* __restrict__ W0, const float* __restrict__ W1,
    const float* __restrict__ W2, const float* __restrict__ W3,
    const float* __restrict__ W4, bf16* __restrict__ outbase,
    const float* __restrict__ bq, const float* __restrict__ u,
    const float* __restrict__ v, float* __restrict__ bu, float* __restrict__ bv2,
    bf16* __restrict__ pe, uint4* __restrict__ pz) {
  int blk = blockIdx.x, t = threadIdx.x;
  __shared__ float tile[32][33];
  __shared__ float red[8];
  if (blk < 4096) {
    // ---- LayerNorm row ----
    int row = blk;
    const float4* xr = (const float4*)(x + (size_t)row * D_);
    float4 vv = xr[t];
    float s  = vv.x + vv.y + vv.z + vv.w;
    float ss = vv.x*vv.x + vv.y*vv.y + vv.z*vv.z + vv.w*vv.w;
    for (int off = 32; off; off >>= 1) {
      s  += __shfl_xor(s, off);
      ss += __shfl_xor(ss, off);
    }
    int wid = t >> 6;
    if ((t & 63) == 0) { red[wid] = s; red[wid + 4] = ss; }
    __syncthreads();
    float S  = red[0] + red[1] + red[2] + red[3];
    float SS = red[4] + red[5] + red[6] + red[7];
    float mu = S * (1.f / 1024.f);
    float rstd = rsqrtf(SS * (1.f / 1024.f) - mu * mu + 1e-5f);
    float4 g  = ((const float4*)gamma)[t];
    float4 bb = ((const float4*)beta)[t];
    bf16x4 o;
    o[0] = (bf16)((vv.x - mu) * rstd * g.x + bb.x);
    o[1] = (bf16)((vv.y - mu) * rstd * g.y + bb.y);
    o[2] = (bf16)((vv.z - mu) * rstd * g.z + bb.z);
    o[3] = (bf16)((vv.w - mu) * rstd * g.w + bb.w);
    *(bf16x4*)(xn + (size_t)row * D_ + t * 4) = o;
  } else if (blk < 9216) {
    // ---- weight transpose fp32 -> bf16 ----
    int idx = blk - 4096;
    int z = idx >> 10, rem = idx & 1023;
    int bx = rem & 31, by = rem >> 5;
    const float* W = z == 0 ? W0 : z == 1 ? W1 : z == 2 ? W2 : z == 3 ? W3 : W4;
    bf16* WT = outbase + (size_t)z * 1024 * 1024;
    int tx = t & 31, ty = t >> 5;
    #pragma unroll
    for (int i = 0; i < 4; i++)
      tile[ty + i * 8][tx] = W[(size_t)(by * 32 + ty + i * 8) * D_ + bx * 32 + tx];
    __syncthreads();
    #pragma unroll
    for (int i = 0; i < 4; i++)
      WT[(size_t)(bx * 32 + ty + i * 8) * D_ + by * 32 + tx] = (bf16)tile[tx][ty + i * 8];
  } else {
    int mblk = blk - 9216;
    if (mblk < 1024) {
      int pos = mblk;
      #pragma unroll
      for (int pp = 0; pp < 2; pp++) {
        int f = t + pp * 256;  // 0..511
        float inv = __expf(-(2.0f * (float)f * (1.0f / 1024.0f)) * 9.210340371976184f);
        float ang = (float)pos * inv;
        float sv, cv;
        __sincosf(ang, &sv, &cv);
        pe[(size_t)pos * D_ + 2 * f]     = (bf16)sv;
        pe[(size_t)pos * D_ + 2 * f + 1] = (bf16)cv;
      }
    } else if (mblk < 1024 + 1568) {
      int i = (mblk - 1024) * 256 + t;   // PPBYTES/16 = 401408 = 1568*256 exactly
      pz[i] = make_uint4(0u, 0u, 0u, 0u);
    } else {
      int c = (mblk - 2592) * 256 + t;
      if (c < 1024) { bu[c] = bq[c] + u[c]; bv2[c] = bq[c] + v[c]; }
    }
  }
}

// ---------------- fused QKV+pos GEMM (single-buffer, R5 structure) ----------------
__global__ __launch_bounds__(256) void gemm_qkvp_kernel(
    const bf16* __restrict__ xn, const bf16* __restrict__ pe,
    const bf16* __restrict__ BT,
    const float* __restrict__ bu, const float* __restrict__ bv2,
    const float* __restrict__ bk, const float* __restrict__ bv,
    bf16* __restrict__ quB, bf16* __restrict__ qvB,
    bf16* __restrict__ kbB, bf16* __restrict__ vtB, bf16* __restrict__ ppd) {
  __shared__ __align__(16) bf16 As[128 * 32];
  __shared__ __align__(16) bf16 Bs[128 * 32];
  int lin = blockIdx.x;
  int swz = (lin & 7) * 104 + (lin >> 3);   // 832/8 = 104
  int m0, n0, sect;
  const bf16* Abase;
  int nrow0;
  if (swz < 768) {
    int bx = swz % 24, by = swz / 24;
    m0 = by * 128; n0 = bx * 128;
    sect = n0 >> 10;
    Abase = xn; nrow0 = n0;
  } else {
    int pp = swz - 768;
    int bx = pp & 7, by = pp >> 3;
    m0 = by * 128; n0 = bx * 128;
    sect = 3;
    Abase = pe; nrow0 = 3072 + n0;
  }
  int t = threadIdx.x, l = t & 63, w = t >> 6;
  int lr = l & 15, lq = l >> 4;
  int wr = w >> 1, wc = w & 1;
  f32x4 acc[4][4];
  #pragma unroll
  for (int mi = 0; mi < 4; mi++)
    #pragma unroll
    for (int ni = 0; ni < 4; ni++) acc[mi][ni] = (f32x4){0.f, 0.f, 0.f, 0.f};
  int srow = l >> 2, scol = (l & 3) * 8;
  for (int kk = 0; kk < 1024; kk += 32) {
    #pragma unroll
    for (int c2 = 0; c2 < 2; c2++) {
      int ch = w * 2 + c2;
      const bf16* ga = Abase + (size_t)(m0 + ch * 16 + srow) * 1024 + kk + scol;
      __builtin_amdgcn_global_load_lds((const AS1 void*)ga, (AS3 void*)(As + ch * 512), 16, 0, 0);
      const bf16* gb = BT + (size_t)(nrow0 + ch * 16 + srow) * 1024 + kk + scol;
      __builtin_amdgcn_global_load_lds((const AS1 void*)gb, (AS3 void*)(Bs + ch * 512), 16, 0, 0);
    }
    __syncthreads();
    bf16x8 af[4], bfv[4];
    #pragma unroll
    for (int mi = 0; mi < 4; mi++)
      af[mi] = *(const bf16x8*)(As + (wr * 64 + mi * 16 + lr) * 32 + lq * 8);
    #pragma unroll
    for (int ni = 0; ni < 4; ni++)
      bfv[ni] = *(const bf16x8*)(Bs + (wc * 64 + ni * 16 + lr) * 32 + lq * 8);
    if (sect == 2) {
      #pragma unroll
      for (int mi = 0; mi < 4; mi++)
        #pragma unroll
        for (int ni = 0; ni < 4; ni++)
          acc[mi][ni] = mfma16(bfv[ni], af[mi], acc[mi][ni]);   // C^T
    } else {
      #pragma unroll
      for (int mi = 0; mi < 4; mi++)
        #pragma unroll
        for (int ni = 0; ni < 4; ni++)
          acc[mi][ni] = mfma16(af[mi], bfv[ni], acc[mi][ni]);
    }
    __syncthreads();
  }
  if (sect == 2) {
    #pragma unroll
    for (int mi = 0; mi < 4; mi++)
      #pragma unroll
      for (int ni = 0; ni < 4; ni++)
        #pragma unroll
        for (int rr = 0; rr < 4; rr++) {
          int wcol = (n0 - 2048) + wc * 64 + ni * 16 + lq * 4 + rr;
          int srw  = m0 + wr * 64 + mi * 16 + lr;
          int b = srw >> 10, s = srw & 1023, h = wcol >> 6, hd = wcol & 63;
          vtB[(((size_t)(b * 16 + h)) * 64 + hd) * 1024 + s] =
              (bf16)(acc[mi][ni][rr] + bv[wcol]);
        }
  } else if (sect == 3) {
    #pragma unroll
    for (int mi = 0; mi < 4; mi++)
      #pragma unroll
      for (int ni = 0; ni < 4; ni++)
        #pragma unroll
        for (int rr = 0; rr < 4; rr++) {
          int row = m0 + wr * 64 + mi * 16 + lq * 4 + rr;
          int col = n0 + wc * 64 + ni * 16 + lr;
          int h = col >> 6, hd = col & 63;
          ppd[((size_t)h * PROWS + POFF + row) * 64 + hd] = (bf16)acc[mi][ni][rr];
        }
  } else {
    #pragma unroll
    for (int mi = 0; mi < 4; mi++)
      #pragma unroll
      for (int ni = 0; ni < 4; ni++)
        #pragma unroll
        for (int rr = 0; rr < 4; rr++) {
          int row = m0 + wr * 64 + mi * 16 + lq * 4 + rr;
          int col = n0 + wc * 64 + ni * 16 + lr;
          float vv = acc[mi][ni][rr];
          int b = row >> 10, s = row & 1023;
          if (sect == 0) {
            int h = col >> 6, hd = col & 63;
            size_t idx = (((size_t)(b * 16 + h)) * 1024 + s) * 64 + hd;
            quB[idx] = (bf16)(vv + bu[col]);
            qvB[idx] = (bf16)(vv + bv2[col]);
          } else {
            int c = col - 1024, h = c >> 6, hd = c & 63;
            size_t idx = (((size_t)(b * 16 + h)) * 1024 + s) * 64 + hd;
            kbB[idx] = (bf16)(vv + bk[c]);
          }
        }
  }
}

// ---------------- final GEMM (single-buffer): d_out fp32 = obB * wtf^T + bf ----------------
__global__ __launch_bounds__(256) void gemm_final_kernel(
    const bf16* __restrict__ A, const bf16* __restrict__ BT,
    const float* __restrict__ bias0, float* __restrict__ out0) {
  __shared__ __align__(16) bf16 As[128 * 32];
  __shared__ __align__(16) bf16 Bs[128 * 32];
  int gx = gridDim.x;
  int lin = blockIdx.x + gx * blockIdx.y;
  int cpx = (gx * gridDim.y) >> 3;
  int swz = (lin & 7) * cpx + (lin >> 3);
  int bx = swz % gx, by = swz / gx;
  int m0 = by * 128, n0 = bx * 128;
  int t = threadIdx.x, l = t & 63, w = t >> 6;
  int lr = l & 15, lq = l >> 4;
  int wr = w >> 1, wc = w & 1;
  f32x4 acc[4][4];
  #pragma unroll
  for (int mi = 0; mi < 4; mi++)
    #pragma unroll
    for (int ni = 0; ni < 4; ni++) acc[mi][ni] = (f32x4){0.f, 0.f, 0.f, 0.f};
  int srow = l >> 2, scol = (l & 3) * 8;
  for (int kk = 0; kk < 1024; kk += 32) {
    #pragma unroll
    for (int c2 = 0; c2 < 2; c2++) {
      int ch = w * 2 + c2;
      const bf16* ga = A + (size_t)(m0 + ch * 16 + srow) * 1024 + kk + scol;
      __builtin_amdgcn_global_load_lds((const AS1 void*)ga, (AS3 void*)(As + ch * 512), 16, 0, 0);
      const bf16* gb = BT + (size_t)(n0 + ch * 16 + srow) * 1024 + kk + scol;
      __builtin_amdgcn_global_load_lds((const AS1 void*)gb, (AS3 void*)(Bs + ch * 512), 16, 0, 0);
    }
    __syncthreads();
    bf16x8 af[4], bfv[4];
    #pragma unroll
    for (int mi = 0; mi < 4; mi++)
      af[mi] = *(const bf16x8*)(As + (wr * 64 + mi * 16 + lr) * 32 + lq * 8);
    #pragma unroll
    for (int ni = 0; ni < 4; ni++)
      bfv[ni] = *(const bf16x8*)(Bs + (wc * 64 + ni * 16 + lr) * 32 + lq * 8);
    #pragma unroll
    for (int mi = 0; mi < 4; mi++)
      #pragma unroll
      for (int ni = 0; ni < 4; ni++)
        acc[mi][ni] = mfma16(af[mi], bfv[ni], acc[mi][ni]);
    __syncthreads();
  }
  #pragma unroll
  for (int mi = 0; mi < 4; mi++)
    #pragma unroll
    for (int ni = 0; ni < 4; ni++)
      #pragma unroll
      for (int rr = 0; rr < 4; rr++) {
        int row = m0 + wr * 64 + mi * 16 + lq * 4 + rr;
        int col = n0 + wc * 64 + ni * 16 + lr;
        out0[(size_t)row * 1024 + col] = acc[mi][ni][rr] + bias0[col];
      }
}

// ---------------- fused relative attention (R4 + p-window register prefetch) ----------------
// 1-D grid 1024; XCD-local decode. 4 waves/block, wave owns 16 q rows; 16 j-tiles.
// LDS caps residency at 2 blocks/CU (2 waves/SIMD) -> VGPR<=256 free; spend 80
// on bpA/bpB double-buffered p-window prefetch (one tile ahead, pure paths).
__global__ __launch_bounds__(256, 2) void attn_kernel(
    const bf16* __restrict__ qu, const bf16* __restrict__ qv,
    const bf16* __restrict__ kb, const bf16* __restrict__ vt,
    const bf16* __restrict__ ppad, bf16* __restrict__ ob) {
  int bid = blockIdx.x;
  int xcd = bid & 7, slot = bid >> 3;
  int g = slot >> 4, qblk = slot & 15;
  int bh = xcd + 8 * g;
  int h = bh & 15, b = bh >> 4;

  int t = threadIdx.x, l = t & 63, wid = t >> 6;
  int lr = l & 15, lq = l >> 4;
  int w0 = qblk * 64 + wid * 16;
  const bf16* quB = qu + (size_t)bh * S_ * 64;
  const bf16* qvB = qv + (size_t)bh * S_ * 64;
  const char* kBy = (const char*)(kb + (size_t)bh * S_ * 64);
  const char* vBy = (const char*)(vt + (size_t)bh * 64 * S_);
  const bf16* pH  = ppad + (size_t)h * PROWS * 64;

  __shared__ __align__(16) bf16 Kbuf[2][4096];   // [64 j][64 k] swizzled
  __shared__ __align__(16) bf16 Vbuf[2][4096];   // [64 d][64 j] swizzled
  __shared__ __align__(16) bf16 G1s[4][16][84];
  __shared__ __align__(16) bf16 G2s[4][16][84];
  bf16* PlW = &G1s[wid][0][0];                   // alias: [16][72], used after G reads

  bf16x8 aqu[2], aqv1[2], aqv2[2];
  #pragma unroll
  for (int ks = 0; ks < 2; ks++) {
    aqu[ks]  = *(const bf16x8*)(quB + (size_t)(w0 + lr) * 64 + ks * 32 + lq * 8);
    aqv1[ks] = *(const bf16x8*)(qvB + (size_t)(w0 + lr) * 64 + ks * 32 + lq * 8);
    aqv2[ks] = *(const bf16x8*)(qvB + (size_t)(w0 + 1 + lr) * 64 + ks * 32 + lq * 8);
  }
  bf16x8 ones;
  #pragma unroll
  for (int e = 0; e < 8; e++) ones[e] = (bf16)1.0f;

  float m_run[4];
  f32x4 accL = (f32x4){0.f, 0.f, 0.f, 0.f};
  f32x4 accO[4];
  #pragma unroll
  for (int rr = 0; rr < 4; rr++) m_run[rr] = -1e30f;
  #pragma unroll
  for (int nf = 0; nf < 4; nf++) accO[nf] = (f32x4){0.f, 0.f, 0.f, 0.f};

  const float SC = 0.045084220f;  // log2(e)/sqrt(1024)

  // staging: 16 chunk-instrs (8 K + 8 V), 4 per wave; dest linear, src pre-swizzled
  int srow8 = l >> 3;            // 0..7
  int scolb = (l & 7) * 16;      // 0..112 byte
  auto stage = [&](int nb, int j0n) {
    #pragma unroll
    for (int ci = 0; ci < 4; ci++) {
      int c = wid * 4 + ci;        // 0..15
      int cc = c & 7;
      int row = cc * 8 + srow8;    // 0..63
      int colsrc = scolb ^ ((row & 7) << 4);
      if (c < 8) {
        const char* src = kBy + (size_t)(j0n + row) * 128 + colsrc;
        __builtin_amdgcn_global_load_lds((const AS1 void*)src,
            (AS3 void*)(&Kbuf[nb][cc * 512]), 16, 0, 0);
      } else {
        const char* src = vBy + (size_t)row * 2048 + j0n * 2 + colsrc;
        __builtin_amdgcn_global_load_lds((const AS1 void*)src,
            (AS3 void*)(&Vbuf[nb][cc * 512]), 16, 0, 0);
      }
    }
  };

  // p-window register prefetch buffers (one tile ahead on pure paths)
  bf16x8 bpA[10], bpB[10];
  auto loadwin = [&](bf16x8 (&bp)[10], int pb) {
    #pragma unroll
    for (int gf = 0; gf < 5; gf++)
      #pragma unroll
      for (int ks = 0; ks < 2; ks++)
        bp[gf * 2 + ks] = *(const bf16x8*)(pH + (size_t)(pb + gf * 16 + lr) * 64 + ks * 32 + lq * 8);
  };

  stage(0, 0);
  // preload tile 0's windows if tile 0 is a pure path (d = w0)
  if (w0 >= 63) loadwin(bpA, 1023 - w0 - 15 + POFF);
  __syncthreads();

  auto tile = [&](int tt, bf16x8 (&bpC)[10], bf16x8 (&bpN)[10]) {
    int j0 = tt * 64;
    int cur = tt & 1;
    if (tt < 15) stage(cur ^ 1, j0 + 64);

    const char* Ks = (const char*)&Kbuf[cur][0];
    const char* Vs = (const char*)&Vbuf[cur][0];
    int d = w0 - j0;

    // AC = (q+u) k^T from swizzled LDS
    f32x4 accS[4];
    __builtin_amdgcn_s_setprio(1);
    #pragma unroll
    for (int nf = 0; nf < 4; nf++) {
      accS[nf] = (f32x4){0.f, 0.f, 0.f, 0.f};
      int rowk = nf * 16 + lr;
      #pragma unroll
      for (int ks = 0; ks < 2; ks++) {
        int off = ((rowk << 7) + (ks << 6) + (lq << 4)) ^ ((rowk & 7) << 4);
        bf16x8 bk8 = *(const bf16x8*)(Ks + off);
        accS[nf] = mfma16(aqu[ks], bk8, accS[nf]);
      }
    }
    __builtin_amdgcn_s_setprio(0);

    // BD windows from prefetched registers (pure paths) or direct (mixed)
    if (d >= 63) {
      #pragma unroll
      for (int gf = 0; gf < 5; gf++) {
        f32x4 gg = (f32x4){0.f, 0.f, 0.f, 0.f};
        gg = mfma16(aqv1[0], bpC[gf * 2 + 0], gg);
        gg = mfma16(aqv1[1], bpC[gf * 2 + 1], gg);
        #pragma unroll
        for (int rr = 0; rr < 4; rr++) G1s[wid][lq * 4 + rr][gf * 16 + lr] = (bf16)gg[rr];
      }
    } else if (d <= -17) {
      #pragma unroll
      for (int gf = 0; gf < 5; gf++) {
        f32x4 gg = (f32x4){0.f, 0.f, 0.f, 0.f};
        gg = mfma16(aqv2[0], bpC[gf * 2 + 0], gg);
        gg = mfma16(aqv2[1], bpC[gf * 2 + 1], gg);
        #pragma unroll
        for (int rr = 0; rr < 4; rr++) G2s[wid][lq * 4 + rr][gf * 16 + lr] = (bf16)gg[rr];
      }
    } else {
      // mixed (<=2 tiles/wave): direct runtime-trimmed loads
      {
        int pb = 1023 - w0 + j0 - 15 + POFF;
        int gmax = (d + 15) >> 4; if (gmax > 4) gmax = 4;
        for (int gf = 0; gf <= gmax; gf++) {
          f32x4 gg = (f32x4){0.f, 0.f, 0.f, 0.f};
          #pragma unroll
          for (int ks = 0; ks < 2; ks++) {
            bf16x8 bp = *(const bf16x8*)(pH + (size_t)(pb + gf * 16 + lr) * 64 + ks * 32 + lq * 8);
            gg = mfma16(aqv1[ks], bp, gg);
          }
          #pragma unroll
          for (int rr = 0; rr < 4; rr++) G1s[wid][lq * 4 + rr][gf * 16 + lr] = (bf16)gg[rr];
        }
      }
      {
        int pb = j0 - w0 - 17 + POFF;
        int t2 = d + 17;
        int gmin = t2 > 0 ? (t2 >> 4) : 0;
        for (int gf = gmin; gf < 5; gf++) {
          f32x4 gg = (f32x4){0.f, 0.f, 0.f, 0.f};
          #pragma unroll
          for (int ks = 0; ks < 2; ks++) {
            bf16x8 bp = *(const bf16x8*)(pH + (size_t)(pb + gf * 16 + lr) * 64 + ks * 32 + lq * 8);
            gg = mfma16(aqv2[ks], bp, gg);
          }
          #pragma unroll
          for (int rr = 0; rr < 4; rr++) G2s[wid][lq * 4 + rr][gf * 16 + lr] = (bf16)gg[rr];
        }
      }
    }

    // issue next tile's p-window prefetch (pure paths only); latency hides
    // under gather+softmax+PV+barrier+stage+AC of this/next tile
    if (tt < 15) {
      int dn = d - 64;
      int j0n = j0 + 64;
      if (dn >= 63)       loadwin(bpN, 1023 - w0 + j0n - 15 + POFF);
      else if (dn <= -17) loadwin(bpN, j0n - w0 - 17 + POFF);
    }

    // gather + softmax (wave-uniform path split)
    float sc[4][4];
    if (d >= 63) {
      #pragma unroll
      for (int nf = 0; nf < 4; nf++)
        #pragma unroll
        for (int rr = 0; rr < 4; rr++) {
          int ii = lq * 4 + rr;
          int u = nf * 16 + lr - ii + 15;
          sc[nf][rr] = (accS[nf][rr] + (float)G1s[wid][ii][u]) * SC;
        }
    } else if (d <= -17) {
      #pragma unroll
      for (int nf = 0; nf < 4; nf++)
        #pragma unroll
        for (int rr = 0; rr < 4; rr++) {
          int ii = lq * 4 + rr;
          int u = nf * 16 + lr - ii + 15;
          sc[nf][rr] = (accS[nf][rr] + (float)G2s[wid][ii][u]) * SC;
        }
    } else {
      #pragma unroll
      for (int nf = 0; nf < 4; nf++)
        #pragma unroll
        for (int rr = 0; rr < 4; rr++) {
          int ii = lq * 4 + rr;
          int jj = nf * 16 + lr;
          int dd = jj - ii;
          int u = dd + 15;
          float g1v = (float)G1s[wid][ii][u];
          float g2v = (float)G2s[wid][ii][u];
          float bd = dd <= d ? g1v : (dd == d + 1 ? 0.f : g2v);
          sc[nf][rr] = (accS[nf][rr] + bd) * SC;
        }
    }

    // defer-max: skip shuffle-max + rescale when within THR of running max
    float lmax[4];
    #pragma unroll
    for (int rr = 0; rr < 4; rr++)
      lmax[rr] = fmaxf(fmaxf(sc[0][rr], sc[1][rr]), fmaxf(sc[2][rr], sc[3][rr]));
    bool ok = (lmax[0] <= m_run[0] + 8.f) && (lmax[1] <= m_run[1] + 8.f) &&
              (lmax[2] <= m_run[2] + 8.f) && (lmax[3] <= m_run[3] + 8.f);
    if (!__all((int)ok)) {
      float rmax[4];
      #pragma unroll
      for (int rr = 0; rr < 4; rr++) rmax[rr] = lmax[rr];
      #pragma unroll
      for (int st = 1; st < 16; st <<= 1)
        #pragma unroll
        for (int rr = 0; rr < 4; rr++) rmax[rr] = fmaxf(rmax[rr], __shfl_xor(rmax[rr], st));
      #pragma unroll
      for (int rr = 0; rr < 4; rr++) {
        float mnew = fmaxf(m_run[rr], rmax[rr]);
        float sv = exp2f(m_run[rr] - mnew);
        m_run[rr] = mnew;
        accL[rr] *= sv;
        #pragma unroll
        for (int nf = 0; nf < 4; nf++) accO[nf][rr] *= sv;
      }
    }

    #pragma unroll
    for (int nf = 0; nf < 4; nf++)
      #pragma unroll
      for (int rr = 0; rr < 4; rr++) {
        float p = exp2f(sc[nf][rr] - m_run[rr]);
        PlW[(lq * 4 + rr) * 72 + nf * 16 + lr] = (bf16)p;
      }

    // PV + row-sum from swizzled LDS V^T
    bf16x8 ap[2];
    #pragma unroll
    for (int ks = 0; ks < 2; ks++)
      ap[ks] = *(const bf16x8*)(PlW + lr * 72 + ks * 32 + lq * 8);
    __builtin_amdgcn_s_setprio(1);
    #pragma unroll
    for (int ks = 0; ks < 2; ks++) accL = mfma16(ap[ks], ones, accL);
    #pragma unroll
    for (int nf = 0; nf < 4; nf++) {
      int rowd = nf * 16 + lr;
      #pragma unroll
      for (int ks = 0; ks < 2; ks++) {
        int off = ((rowd << 7) + (ks << 6) + (lq << 4)) ^ ((rowd & 7) << 4);
        bf16x8 bv8 = *(const bf16x8*)(Vs + off);
        accO[nf] = mfma16(ap[ks], bv8, accO[nf]);
      }
    }
    __builtin_amdgcn_s_setprio(0);

    __syncthreads();
  };

  #pragma unroll 1
  for (int tt = 0; tt < 16; tt += 2) {
    tile(tt,     bpA, bpB);
    tile(tt + 1, bpB, bpA);
  }

  #pragma unroll
  for (int nf = 0; nf < 4; nf++)
    #pragma unroll
    for (int rr = 0; rr < 4; rr++) {
      int i = w0 + lq * 4 + rr;
      float o = accO[nf][rr] / accL[rr];
      ob[((size_t)(b * S_ + i)) * 1024 + h * 64 + nf * 16 + lr] = (bf16)o;
    }
}

// ---------------- launch ----------------
extern "C" void kernel_launch(void* const* d_in, const int* in_sizes, int n_in,
                              void* d_out, int out_size, void* d_ws, size_t ws_size,
                              hipStream_t stream) {
  const float* x     = (const float*)d_in[0];
  const float* Wq    = (const float*)d_in[1];
  const float* bq    = (const float*)d_in[2];
  const float* Wk    = (const float*)d_in[3];
  const float* bk    = (const float*)d_in[4];
  const float* Wv    = (const float*)d_in[5];
  const float* bv    = (const float*)d_in[6];
  const float* Wpos  = (const float*)d_in[7];
  const float* Wf    = (const float*)d_in[8];
  const float* bf_   = (const float*)d_in[9];
  const float* u     = (const float*)d_in[10];
  const float* v     = (const float*)d_in[11];
  const float* gamma = (const float*)d_in[12];
  const float* beta  = (const float*)d_in[13];

  char* ws = (char*)d_ws;
  bf16* xn  = (bf16*)(ws + OXN);
  bf16* wtq = (bf16*)(ws + OWTQ);   // BT[5120][1024] base (q,k,v,pos,f)
  bf16* wtf = (bf16*)(ws + OWTF);
  bf16* pe  = (bf16*)(ws + OPE);
  bf16* quB = (bf16*)(ws + OQU);
  bf16* qvB = (bf16*)(ws + OQV);
  bf16* kbB = (bf16*)(ws + OKB);
  bf16* vtB = (bf16*)(ws + OVT);
  bf16* ppd = (bf16*)(ws + OPP);
  bf16* obB = (bf16*)(ws + OOB);
  float* bu  = (float*)(ws + OBU);
  float* bv2 = (float*)(ws + OBV2);

  prep_kernel<<<11812, 256, 0, stream>>>(x, gamma, beta, xn,
                                         Wq, Wk, Wv, Wpos, Wf, wtq,
                                         bq, u, v, bu, bv2, pe, (uint4*)(ws + OPP));

  gemm_qkvp_kernel<<<832, 256, 0, stream>>>(xn, pe, wtq, bu, bv2, bk, bv,
                                            quB, qvB, kbB, vtB, ppd);

  attn_kernel<<<1024, 256, 0, stream>>>(quB, qvB, kbB, vtB, ppd, obB);

  gemm_final_kernel<<<dim3(8, 32), 256, 0, stream>>>(obB, wtf, bf_, (float*)d_out);
}